// Round 3
// baseline (262.498 us; speedup 1.0000x reference)
//
#include <hip/hip_runtime.h>
#include <hip/hip_cooperative_groups.h>
#include <math.h>

namespace cg = cooperative_groups;

#define N_NODES 16384
#define CIN 128
#define HOUT 256          // HEADS * OUT_CH
#define OUTC 128
#define NEG_ATT 0.2f
#define NEG_ACT 0.01f
#define BN_EPS 1e-5f

typedef short short8 __attribute__((ext_vector_type(8)));
typedef float f32x4 __attribute__((ext_vector_type(4)));

static __device__ __forceinline__ unsigned short f2bf(float f) {
    unsigned int u = __float_as_uint(f);
    unsigned int r = (u + 0x7FFFu + ((u >> 16) & 1u)) >> 16;   // round-nearest-even
    return (unsigned short)r;
}
static __device__ __forceinline__ float bf2f(unsigned short s) {
    return __uint_as_float(((unsigned int)s) << 16);
}

// ---------------- MFMA GEMM: h[n][o] = sum_k x[b][k][s] * lin_w[k][o] + lin_b[o] ----------
// 64x64 tile, K=128 staged once. A_s[n][k], Bt_s[o][k], rows padded to 136 bf16 (272 B).
// Also zeros deg (16 ints/block) and gsum/gsumsq (block 0) for later kernels.
#define LDP 136
__global__ __launch_bounds__(256) void gemm_kernel(const float* __restrict__ x,
                                                   const float* __restrict__ lin_w,
                                                   const float* __restrict__ lin_b,
                                                   unsigned short* __restrict__ h,
                                                   int* __restrict__ deg,
                                                   float* __restrict__ gz) {
    __shared__ __align__(16) unsigned short A_s[64 * LDP];
    __shared__ __align__(16) unsigned short Bt_s[64 * LDP];
    const int t = threadIdx.x;
    const int bid = blockIdx.x;

    if (t < 16) deg[bid * 16 + t] = 0;            // zero deg for csr kernel
    if (bid == 0) gz[t] = 0.f;                    // zero gsum+gsumsq (256 floats)

    const int node0 = (bid >> 2) * 64;
    const int o0 = (bid & 3) * 64;
    const int b = node0 >> 13;
    const int s0 = node0 & 8191;

    // staging: 4x4 micro-tile register transpose, vector LDS writes
    const int nt = t & 15;           // n-quad
    const int kt = t >> 4;           // k-quad (0..15)
#pragma unroll
    for (int p = 0; p < 2; p++) {
        const int kb = p * 64 + kt * 4;
        float4 ar[4], br[4];
#pragma unroll
        for (int r = 0; r < 4; r++) {
            ar[r] = *(const float4*)&x[((b * CIN + kb + r) << 13) + s0 + nt * 4];
            br[r] = *(const float4*)&lin_w[(kb + r) * HOUT + o0 + nt * 4];
        }
#pragma unroll
        for (int j = 0; j < 4; j++) {
            ushort4 va, vb;
            va.x = f2bf(((const float*)&ar[0])[j]);
            va.y = f2bf(((const float*)&ar[1])[j]);
            va.z = f2bf(((const float*)&ar[2])[j]);
            va.w = f2bf(((const float*)&ar[3])[j]);
            vb.x = f2bf(((const float*)&br[0])[j]);
            vb.y = f2bf(((const float*)&br[1])[j]);
            vb.z = f2bf(((const float*)&br[2])[j]);
            vb.w = f2bf(((const float*)&br[3])[j]);
            *(ushort4*)&A_s[(nt * 4 + j) * LDP + kb] = va;
            *(ushort4*)&Bt_s[(nt * 4 + j) * LDP + kb] = vb;
        }
    }
    __syncthreads();

    const int w = t >> 6;            // wave: rows m0..m0+15
    const int lane = t & 63;
    const int lrow = lane & 15;
    const int lquad = lane >> 4;
    const int m0 = w * 16;

    short8 afr[4];
#pragma unroll
    for (int ks = 0; ks < 4; ks++)
        afr[ks] = *(const short8*)&A_s[(m0 + lrow) * LDP + ks * 32 + lquad * 8];

    f32x4 acc[4];
#pragma unroll
    for (int c = 0; c < 4; c++) { acc[c][0] = 0.f; acc[c][1] = 0.f; acc[c][2] = 0.f; acc[c][3] = 0.f; }

#pragma unroll
    for (int c = 0; c < 4; c++) {
#pragma unroll
        for (int ks = 0; ks < 4; ks++) {
            short8 bfr = *(const short8*)&Bt_s[(c * 16 + lrow) * LDP + ks * 32 + lquad * 8];
            acc[c] = __builtin_amdgcn_mfma_f32_16x16x32_bf16(afr[ks], bfr, acc[c], 0, 0, 0);
        }
    }

    // D mapping: col = lane&15, row = (lane>>4)*4 + reg   [m89-verified]
#pragma unroll
    for (int c = 0; c < 4; c++) {
        const int col = o0 + c * 16 + lrow;
        const float lb = lin_b[col];
#pragma unroll
        for (int r = 0; r < 4; r++) {
            const int n = node0 + m0 + lquad * 4 + r;
            h[n * HOUT + col] = f2bf(acc[c][r] + lb);
        }
    }
}

// ---------------- cooperative CSR build: count -> scan -> scatter ----------------
__global__ __launch_bounds__(256) void csr_kernel(const int* __restrict__ edges, int E,
                                                  int* __restrict__ deg,
                                                  int* __restrict__ row_ptr,
                                                  int* __restrict__ cursor,
                                                  int* __restrict__ csr,
                                                  int* __restrict__ partial) {
    cg::grid_group grid = cg::this_grid();
    const int t = threadIdx.x;
    const int bid = blockIdx.x;
    __shared__ int excl_s[64];

    // P1: count (deg pre-zeroed by gemm_kernel)
    for (int e = bid * 256 + t; e < E; e += 256 * 256)
        atomicAdd(&deg[edges[E + e]], 1);
    grid.sync();

    // P2: per-block inclusive scan of 64 degrees (wave 0)
    if (t < 64) {
        int d = deg[bid * 64 + t];
        int v = d;
#pragma unroll
        for (int off = 1; off < 64; off <<= 1) {
            int u = __shfl_up(v, off);
            if (t >= off) v += u;
        }
        excl_s[t] = v - d;
        if (t == 63) partial[bid] = v;
    }
    grid.sync();

    // P3: every block computes its global offset = sum partial[j<bid], writes row_ptr/cursor
    if (t < 64) {
        int s = 0;
        for (int j = t; j < bid; j += 64) s += partial[j];
#pragma unroll
        for (int off = 1; off < 64; off <<= 1) s += __shfl_xor(s, off);
        int rp = s + excl_s[t];
        row_ptr[bid * 64 + t] = rp;
        cursor[bid * 64 + t] = rp;
        if (bid == 255 && t == 63) row_ptr[N_NODES] = s + excl_s[63] + deg[N_NODES - 1];
    }
    grid.sync();

    // P4: scatter
    for (int e = bid * 256 + t; e < E; e += 256 * 256) {
        int src = edges[e];
        int d = edges[E + e];
        int p = atomicAdd(&cursor[d], 1);
        csr[p] = src;
    }
}

// ---------------- GAT: wave does 4 nodes, 8-wide online softmax, fused BN stats -----------
__global__ __launch_bounds__(256) void gat_kernel(const unsigned short* __restrict__ h,
                                                  const int* __restrict__ row_ptr,
                                                  const int* __restrict__ csr,
                                                  const float* __restrict__ att,
                                                  const float* __restrict__ gat_bias,
                                                  float* __restrict__ gat,
                                                  float* __restrict__ gsum,
                                                  float* __restrict__ gsumsq) {
    const int t = threadIdx.x;
    const int lane = t & 63;
    const int w = t >> 6;
    __shared__ float ssum[128], ssq[128];
    if (t < 128) { ssum[t] = 0.f; ssq[t] = 0.f; }
    __syncthreads();

    const ushort4* __restrict__ h4 = (const ushort4*)h;
    float4 a4 = ((const float4*)att)[lane];
    float4 gb = ((const float4*)gat_bias)[lane & 31];
    float st[4] = {0.f, 0.f, 0.f, 0.f}, sq[4] = {0.f, 0.f, 0.f, 0.f};

    for (int i = 0; i < 4; i++) {
        const int node = (blockIdx.x << 4) + (w << 2) + i;
        ushort4 hd4 = h4[(node << 6) + lane];
        float hdx = bf2f(hd4.x), hdy = bf2f(hd4.y), hdz = bf2f(hd4.z), hdw = bf2f(hd4.w);
        const int beg = row_ptr[node];
        const int cnt = row_ptr[node + 1] - beg + 1;   // + self loop (e==0)
        float m = -INFINITY, denom = 0.f;
        float4 acc = make_float4(0.f, 0.f, 0.f, 0.f);

        for (int base = 0; base < cnt; base += 8) {
            int j[8];
#pragma unroll
            for (int u = 0; u < 8; u++) {
                int e = base + u;
                j[u] = (e == 0 || e >= cnt) ? node : csr[beg + e - 1];
            }
            float4 hj[8];
            float p[8];
#pragma unroll
            for (int u = 0; u < 8; u++) {
                ushort4 hv = h4[(j[u] << 6) + lane];
                hj[u].x = bf2f(hv.x); hj[u].y = bf2f(hv.y);
                hj[u].z = bf2f(hv.z); hj[u].w = bf2f(hv.w);
                float vx = hj[u].x + hdx; vx = vx > 0.f ? vx : NEG_ATT * vx;
                float vy = hj[u].y + hdy; vy = vy > 0.f ? vy : NEG_ATT * vy;
                float vz = hj[u].z + hdz; vz = vz > 0.f ? vz : NEG_ATT * vz;
                float vw = hj[u].w + hdw; vw = vw > 0.f ? vw : NEG_ATT * vw;
                p[u] = vx * a4.x + vy * a4.y + vz * a4.z + vw * a4.w;
            }
#pragma unroll
            for (int s = 1; s <= 16; s <<= 1) {
#pragma unroll
                for (int u = 0; u < 8; u++) p[u] += __shfl_xor(p[u], s);
            }
#pragma unroll
            for (int u = 0; u < 8; u++)
                if (base + u >= cnt) p[u] = -INFINITY;
            float nm = m;
#pragma unroll
            for (int u = 0; u < 8; u++) nm = fmaxf(nm, p[u]);
            float scale = __expf(m - nm);
            float wt[8];
#pragma unroll
            for (int u = 0; u < 8; u++) wt[u] = __expf(p[u] - nm);
            float wsum = 0.f;
#pragma unroll
            for (int u = 0; u < 8; u++) wsum += wt[u];
            denom = denom * scale + wsum;
            float ax = acc.x * scale, ay = acc.y * scale, az = acc.z * scale, aw = acc.w * scale;
#pragma unroll
            for (int u = 0; u < 8; u++) {
                ax = fmaf(wt[u], hj[u].x, ax);
                ay = fmaf(wt[u], hj[u].y, ay);
                az = fmaf(wt[u], hj[u].z, az);
                aw = fmaf(wt[u], hj[u].w, aw);
            }
            acc.x = ax; acc.y = ay; acc.z = az; acc.w = aw;
            m = nm;
        }
        float inv = 1.0f / denom;
        float rx = acc.x * inv, ry = acc.y * inv, rz = acc.z * inv, rw = acc.w * inv;
        rx += __shfl_xor(rx, 32);
        ry += __shfl_xor(ry, 32);
        rz += __shfl_xor(rz, 32);
        rw += __shfl_xor(rw, 32);
        if (lane < 32) {
            float4 o;
            o.x = 0.5f * rx + gb.x;
            o.y = 0.5f * ry + gb.y;
            o.z = 0.5f * rz + gb.z;
            o.w = 0.5f * rw + gb.w;
            ((float4*)gat)[(node << 5) + lane] = o;
            st[0] += o.x; sq[0] += o.x * o.x;
            st[1] += o.y; sq[1] += o.y * o.y;
            st[2] += o.z; sq[2] += o.z * o.z;
            st[3] += o.w; sq[3] += o.w * o.w;
        }
    }
    if (lane < 32) {
#pragma unroll
        for (int c = 0; c < 4; c++) {
            atomicAdd(&ssum[(lane << 2) + c], st[c]);
            atomicAdd(&ssq[(lane << 2) + c], sq[c]);
        }
    }
    __syncthreads();
    if (t < 128) {
        atomicAdd(&gsum[t], ssum[t]);
        atomicAdd(&gsumsq[t], ssq[t]);
    }
}

// ---------------- epilogue: BN finalize + affine + lrelu + transpose to (B,C,D,H,W) --------
__global__ __launch_bounds__(256) void epilogue_kernel(const float* __restrict__ gat,
                                                       const float* __restrict__ gsum,
                                                       const float* __restrict__ gsumsq,
                                                       const float* __restrict__ gamma,
                                                       const float* __restrict__ beta,
                                                       float* __restrict__ out) {
    __shared__ float tile[64 * 129];
    __shared__ float sc[128], sh[128];
    const int t = threadIdx.x;
    if (t < 128) {
        const float invN = 1.0f / (float)N_NODES;
        float mean = gsum[t] * invN;
        float var = gsumsq[t] * invN - mean * mean;
        float rstd = rsqrtf(var + BN_EPS);
        float s = gamma[t] * rstd;
        sc[t] = s;
        sh[t] = beta[t] - mean * s;
    }
    __syncthreads();
    const int n0 = blockIdx.x * 64;
    const int b = n0 >> 13;
    const int s0 = n0 & 8191;
#pragma unroll
    for (int k = 0; k < 32; k++) {
        int f = t + k * 256;
        int nl = f >> 7;
        int c = f & 127;
        float v = gat[(n0 << 7) + f];
        v = v * sc[c] + sh[c];
        v = v > 0.f ? v : NEG_ACT * v;
        tile[nl * 129 + c] = v;
    }
    __syncthreads();
    const int sl = t & 63;
    const int c0 = t >> 6;
#pragma unroll
    for (int k = 0; k < 32; k++) {
        int c = c0 + (k << 2);
        out[((b * OUTC + c) << 13) + s0 + sl] = tile[sl * 129 + c];
    }
}

extern "C" void kernel_launch(void* const* d_in, const int* in_sizes, int n_in,
                              void* d_out, int out_size, void* d_ws, size_t ws_size,
                              hipStream_t stream) {
    const float* x        = (const float*)d_in[0];
    const int*   edges    = (const int*)d_in[1];
    const float* lin_w    = (const float*)d_in[2];
    const float* lin_b    = (const float*)d_in[3];
    const float* att      = (const float*)d_in[4];
    const float* gat_bias = (const float*)d_in[5];
    const float* bn_gamma = (const float*)d_in[6];
    const float* bn_beta  = (const float*)d_in[7];
    float* out = (float*)d_out;
    int E = in_sizes[1] / 2;

    char* ws = (char*)d_ws;
    unsigned short* h = (unsigned short*)(ws);            // 8 MB
    float* gat     = (float*)(ws + 8388608);              // 8 MB
    int*   deg     = (int*)(ws + 16777216);               // 64 KB
    int*   row_ptr = (int*)(ws + 16842752);               // 16385 ints
    int*   cursor  = (int*)(ws + 16908544);               // 64 KB
    int*   csr     = (int*)(ws + 16974080);               // E ints
    int*   partial = (int*)(ws + 17825792);               // 256 ints
    float* gsum    = (float*)(ws + 17827840);             // 128
    float* gsumsq  = gsum + 128;                          // 128

    gemm_kernel<<<1024, 256, 0, stream>>>(x, lin_w, lin_b, h, deg, gsum);

    const int* edges_a = edges;
    int E_a = E;
    int* deg_a = deg; int* row_ptr_a = row_ptr; int* cursor_a = cursor;
    int* csr_a = csr; int* partial_a = partial;
    void* cargs[] = {&edges_a, &E_a, &deg_a, &row_ptr_a, &cursor_a, &csr_a, &partial_a};
    hipLaunchCooperativeKernel((void*)csr_kernel, dim3(256), dim3(256), cargs, 0, stream);

    gat_kernel<<<N_NODES / 16, 256, 0, stream>>>(h, row_ptr, csr, att, gat_bias, gat, gsum, gsumsq);
    epilogue_kernel<<<N_NODES / 64, 256, 0, stream>>>(gat, gsum, gsumsq, bn_gamma, bn_beta, out);
}

// Round 4
// 164.289 us; speedup vs baseline: 1.5978x; 1.5978x over previous
//
#include <hip/hip_runtime.h>
#include <math.h>

#define N_NODES 16384
#define CIN 128
#define HOUT 256          // HEADS * OUT_CH
#define OUTC 128
#define NEG_ATT 0.2f
#define NEG_ACT 0.01f
#define BN_EPS 1e-5f

typedef short short8 __attribute__((ext_vector_type(8)));
typedef float f32x4 __attribute__((ext_vector_type(4)));

static __device__ __forceinline__ unsigned short f2bf(float f) {
    unsigned int u = __float_as_uint(f);
    unsigned int r = (u + 0x7FFFu + ((u >> 16) & 1u)) >> 16;   // round-nearest-even
    return (unsigned short)r;
}
static __device__ __forceinline__ float bf2f(unsigned short s) {
    return __uint_as_float(((unsigned int)s) << 16);
}

// ---------------- MFMA GEMM: h[n][o] = sum_k x[b][k][s] * lin_w[k][o] + lin_b[o] ----------
// 64x64 tile, K=128 staged once. A_s[n][k], Bt_s[o][k], rows padded to 136 bf16 (272 B).
// Also zeros deg (16 ints/block) and gsum/gsumsq (block 0) for later kernels.
#define LDP 136
__global__ __launch_bounds__(256) void gemm_kernel(const float* __restrict__ x,
                                                   const float* __restrict__ lin_w,
                                                   const float* __restrict__ lin_b,
                                                   unsigned short* __restrict__ h,
                                                   int* __restrict__ deg,
                                                   float* __restrict__ gz) {
    __shared__ __align__(16) unsigned short A_s[64 * LDP];
    __shared__ __align__(16) unsigned short Bt_s[64 * LDP];
    const int t = threadIdx.x;
    const int bid = blockIdx.x;

    if (t < 16) deg[bid * 16 + t] = 0;            // zero deg for count_kernel
    if (bid == 0) gz[t] = 0.f;                    // zero gsum+gsumsq (256 floats)

    const int node0 = (bid >> 2) * 64;
    const int o0 = (bid & 3) * 64;
    const int b = node0 >> 13;
    const int s0 = node0 & 8191;

    // staging: 4x4 micro-tile register transpose, vector LDS writes
    const int nt = t & 15;           // n-quad
    const int kt = t >> 4;           // k-quad (0..15)
#pragma unroll
    for (int p = 0; p < 2; p++) {
        const int kb = p * 64 + kt * 4;
        float4 ar[4], br[4];
#pragma unroll
        for (int r = 0; r < 4; r++) {
            ar[r] = *(const float4*)&x[((b * CIN + kb + r) << 13) + s0 + nt * 4];
            br[r] = *(const float4*)&lin_w[(kb + r) * HOUT + o0 + nt * 4];
        }
#pragma unroll
        for (int j = 0; j < 4; j++) {
            ushort4 va, vb;
            va.x = f2bf(((const float*)&ar[0])[j]);
            va.y = f2bf(((const float*)&ar[1])[j]);
            va.z = f2bf(((const float*)&ar[2])[j]);
            va.w = f2bf(((const float*)&ar[3])[j]);
            vb.x = f2bf(((const float*)&br[0])[j]);
            vb.y = f2bf(((const float*)&br[1])[j]);
            vb.z = f2bf(((const float*)&br[2])[j]);
            vb.w = f2bf(((const float*)&br[3])[j]);
            *(ushort4*)&A_s[(nt * 4 + j) * LDP + kb] = va;
            *(ushort4*)&Bt_s[(nt * 4 + j) * LDP + kb] = vb;
        }
    }
    __syncthreads();

    const int w = t >> 6;            // wave: rows m0..m0+15
    const int lane = t & 63;
    const int lrow = lane & 15;
    const int lquad = lane >> 4;
    const int m0 = w * 16;

    short8 afr[4];
#pragma unroll
    for (int ks = 0; ks < 4; ks++)
        afr[ks] = *(const short8*)&A_s[(m0 + lrow) * LDP + ks * 32 + lquad * 8];

    f32x4 acc[4];
#pragma unroll
    for (int c = 0; c < 4; c++) { acc[c][0] = 0.f; acc[c][1] = 0.f; acc[c][2] = 0.f; acc[c][3] = 0.f; }

#pragma unroll
    for (int c = 0; c < 4; c++) {
#pragma unroll
        for (int ks = 0; ks < 4; ks++) {
            short8 bfr = *(const short8*)&Bt_s[(c * 16 + lrow) * LDP + ks * 32 + lquad * 8];
            acc[c] = __builtin_amdgcn_mfma_f32_16x16x32_bf16(afr[ks], bfr, acc[c], 0, 0, 0);
        }
    }

    // D mapping: col = lane&15, row = (lane>>4)*4 + reg   [m89-verified]
#pragma unroll
    for (int c = 0; c < 4; c++) {
        const int col = o0 + c * 16 + lrow;
        const float lb = lin_b[col];
#pragma unroll
        for (int r = 0; r < 4; r++) {
            const int n = node0 + m0 + lquad * 4 + r;
            h[n * HOUT + col] = f2bf(acc[c][r] + lb);
        }
    }
}

// ---------------- CSR build (3 small dispatches; grid.sync measured ~30us -> never again) --
__global__ void count_kernel(const int* __restrict__ dst, int* __restrict__ deg, int E) {
    int e = blockIdx.x * 256 + threadIdx.x;
    if (e < E) atomicAdd(&deg[dst[e]], 1);
}

// one block, 1024 threads, 16 nodes each (16384 total)
__global__ __launch_bounds__(1024) void scan_kernel(const int* __restrict__ deg,
                                                    int* __restrict__ row_ptr,
                                                    int* __restrict__ cursor) {
    __shared__ int sums[1024];
    const int t = threadIdx.x;
    int local[16];
    int s = 0;
#pragma unroll
    for (int k = 0; k < 16; k++) {
        local[k] = deg[t * 16 + k];
        s += local[k];
    }
    sums[t] = s;
    __syncthreads();
    for (int off = 1; off < 1024; off <<= 1) {
        int v = (t >= off) ? sums[t - off] : 0;
        __syncthreads();
        sums[t] += v;
        __syncthreads();
    }
    int run = sums[t] - s;   // exclusive
#pragma unroll
    for (int k = 0; k < 16; k++) {
        row_ptr[t * 16 + k] = run;
        cursor[t * 16 + k] = run;
        run += local[k];
    }
    if (t == 1023) row_ptr[N_NODES] = run;
}

__global__ void scatter_kernel(const int* __restrict__ edges, int* __restrict__ cursor,
                               int* __restrict__ csr, int E) {
    int e = blockIdx.x * 256 + threadIdx.x;
    if (e < E) {
        int s = edges[e];
        int d = edges[E + e];
        int p = atomicAdd(&cursor[d], 1);
        csr[p] = s;
    }
}

// ---------------- GAT: wave does 4 nodes, 8-wide online softmax, fused BN stats -----------
__global__ __launch_bounds__(256) void gat_kernel(const unsigned short* __restrict__ h,
                                                  const int* __restrict__ row_ptr,
                                                  const int* __restrict__ csr,
                                                  const float* __restrict__ att,
                                                  const float* __restrict__ gat_bias,
                                                  float* __restrict__ gat,
                                                  float* __restrict__ gsum,
                                                  float* __restrict__ gsumsq) {
    const int t = threadIdx.x;
    const int lane = t & 63;
    const int w = t >> 6;
    __shared__ float ssum[128], ssq[128];
    if (t < 128) { ssum[t] = 0.f; ssq[t] = 0.f; }
    __syncthreads();

    const ushort4* __restrict__ h4 = (const ushort4*)h;
    float4 a4 = ((const float4*)att)[lane];
    float4 gb = ((const float4*)gat_bias)[lane & 31];
    float st[4] = {0.f, 0.f, 0.f, 0.f}, sq[4] = {0.f, 0.f, 0.f, 0.f};

    for (int i = 0; i < 4; i++) {
        const int node = (blockIdx.x << 4) + (w << 2) + i;
        ushort4 hd4 = h4[(node << 6) + lane];
        float hdx = bf2f(hd4.x), hdy = bf2f(hd4.y), hdz = bf2f(hd4.z), hdw = bf2f(hd4.w);
        const int beg = row_ptr[node];
        const int cnt = row_ptr[node + 1] - beg + 1;   // + self loop (e==0)
        float m = -INFINITY, denom = 0.f;
        float4 acc = make_float4(0.f, 0.f, 0.f, 0.f);

        for (int base = 0; base < cnt; base += 8) {
            int j[8];
#pragma unroll
            for (int u = 0; u < 8; u++) {
                int e = base + u;
                j[u] = (e == 0 || e >= cnt) ? node : csr[beg + e - 1];
            }
            float4 hj[8];
            float p[8];
#pragma unroll
            for (int u = 0; u < 8; u++) {
                ushort4 hv = h4[(j[u] << 6) + lane];
                hj[u].x = bf2f(hv.x); hj[u].y = bf2f(hv.y);
                hj[u].z = bf2f(hv.z); hj[u].w = bf2f(hv.w);
                float vx = hj[u].x + hdx; vx = vx > 0.f ? vx : NEG_ATT * vx;
                float vy = hj[u].y + hdy; vy = vy > 0.f ? vy : NEG_ATT * vy;
                float vz = hj[u].z + hdz; vz = vz > 0.f ? vz : NEG_ATT * vz;
                float vw = hj[u].w + hdw; vw = vw > 0.f ? vw : NEG_ATT * vw;
                p[u] = vx * a4.x + vy * a4.y + vz * a4.z + vw * a4.w;
            }
#pragma unroll
            for (int s = 1; s <= 16; s <<= 1) {
#pragma unroll
                for (int u = 0; u < 8; u++) p[u] += __shfl_xor(p[u], s);
            }
#pragma unroll
            for (int u = 0; u < 8; u++)
                if (base + u >= cnt) p[u] = -INFINITY;
            float nm = m;
#pragma unroll
            for (int u = 0; u < 8; u++) nm = fmaxf(nm, p[u]);
            float scale = __expf(m - nm);
            float wt[8];
#pragma unroll
            for (int u = 0; u < 8; u++) wt[u] = __expf(p[u] - nm);
            float wsum = 0.f;
#pragma unroll
            for (int u = 0; u < 8; u++) wsum += wt[u];
            denom = denom * scale + wsum;
            float ax = acc.x * scale, ay = acc.y * scale, az = acc.z * scale, aw = acc.w * scale;
#pragma unroll
            for (int u = 0; u < 8; u++) {
                ax = fmaf(wt[u], hj[u].x, ax);
                ay = fmaf(wt[u], hj[u].y, ay);
                az = fmaf(wt[u], hj[u].z, az);
                aw = fmaf(wt[u], hj[u].w, aw);
            }
            acc.x = ax; acc.y = ay; acc.z = az; acc.w = aw;
            m = nm;
        }
        float inv = 1.0f / denom;
        float rx = acc.x * inv, ry = acc.y * inv, rz = acc.z * inv, rw = acc.w * inv;
        rx += __shfl_xor(rx, 32);
        ry += __shfl_xor(ry, 32);
        rz += __shfl_xor(rz, 32);
        rw += __shfl_xor(rw, 32);
        if (lane < 32) {
            float4 o;
            o.x = 0.5f * rx + gb.x;
            o.y = 0.5f * ry + gb.y;
            o.z = 0.5f * rz + gb.z;
            o.w = 0.5f * rw + gb.w;
            ((float4*)gat)[(node << 5) + lane] = o;
            st[0] += o.x; sq[0] += o.x * o.x;
            st[1] += o.y; sq[1] += o.y * o.y;
            st[2] += o.z; sq[2] += o.z * o.z;
            st[3] += o.w; sq[3] += o.w * o.w;
        }
    }
    if (lane < 32) {
#pragma unroll
        for (int c = 0; c < 4; c++) {
            atomicAdd(&ssum[(lane << 2) + c], st[c]);
            atomicAdd(&ssq[(lane << 2) + c], sq[c]);
        }
    }
    __syncthreads();
    if (t < 128) {
        atomicAdd(&gsum[t], ssum[t]);
        atomicAdd(&gsumsq[t], ssq[t]);
    }
}

// ---------------- epilogue: BN finalize + affine + lrelu + transpose to (B,C,D,H,W) --------
__global__ __launch_bounds__(256) void epilogue_kernel(const float* __restrict__ gat,
                                                       const float* __restrict__ gsum,
                                                       const float* __restrict__ gsumsq,
                                                       const float* __restrict__ gamma,
                                                       const float* __restrict__ beta,
                                                       float* __restrict__ out) {
    __shared__ float tile[64 * 129];
    __shared__ float sc[128], sh[128];
    const int t = threadIdx.x;
    if (t < 128) {
        const float invN = 1.0f / (float)N_NODES;
        float mean = gsum[t] * invN;
        float var = gsumsq[t] * invN - mean * mean;
        float rstd = rsqrtf(var + BN_EPS);
        float s = gamma[t] * rstd;
        sc[t] = s;
        sh[t] = beta[t] - mean * s;
    }
    __syncthreads();
    const int n0 = blockIdx.x * 64;
    const int b = n0 >> 13;
    const int s0 = n0 & 8191;
#pragma unroll
    for (int k = 0; k < 32; k++) {
        int f = t + k * 256;
        int nl = f >> 7;
        int c = f & 127;
        float v = gat[(n0 << 7) + f];
        v = v * sc[c] + sh[c];
        v = v > 0.f ? v : NEG_ACT * v;
        tile[nl * 129 + c] = v;
    }
    __syncthreads();
    const int sl = t & 63;
    const int c0 = t >> 6;
#pragma unroll
    for (int k = 0; k < 32; k++) {
        int c = c0 + (k << 2);
        out[((b * OUTC + c) << 13) + s0 + sl] = tile[sl * 129 + c];
    }
}

extern "C" void kernel_launch(void* const* d_in, const int* in_sizes, int n_in,
                              void* d_out, int out_size, void* d_ws, size_t ws_size,
                              hipStream_t stream) {
    const float* x        = (const float*)d_in[0];
    const int*   edges    = (const int*)d_in[1];
    const float* lin_w    = (const float*)d_in[2];
    const float* lin_b    = (const float*)d_in[3];
    const float* att      = (const float*)d_in[4];
    const float* gat_bias = (const float*)d_in[5];
    const float* bn_gamma = (const float*)d_in[6];
    const float* bn_beta  = (const float*)d_in[7];
    float* out = (float*)d_out;
    int E = in_sizes[1] / 2;

    char* ws = (char*)d_ws;
    unsigned short* h = (unsigned short*)(ws);            // 8 MB
    float* gat     = (float*)(ws + 8388608);              // 8 MB
    int*   deg     = (int*)(ws + 16777216);               // 64 KB
    int*   row_ptr = (int*)(ws + 16842752);               // 16385 ints
    int*   cursor  = (int*)(ws + 16908544);               // 64 KB
    int*   csr     = (int*)(ws + 16974080);               // E ints
    float* gsum    = (float*)(ws + 17825792);             // 128
    float* gsumsq  = gsum + 128;                          // 128

    gemm_kernel<<<1024, 256, 0, stream>>>(x, lin_w, lin_b, h, deg, gsum);
    count_kernel<<<(E + 255) / 256, 256, 0, stream>>>(edges + E, deg, E);
    scan_kernel<<<1, 1024, 0, stream>>>(deg, row_ptr, cursor);
    scatter_kernel<<<(E + 255) / 256, 256, 0, stream>>>(edges, cursor, csr, E);
    gat_kernel<<<N_NODES / 16, 256, 0, stream>>>(h, row_ptr, csr, att, gat_bias, gat, gsum, gsumsq);
    epilogue_kernel<<<N_NODES / 64, 256, 0, stream>>>(gat, gsum, gsumsq, bn_gamma, bn_beta, out);
}

// Round 5
// 158.256 us; speedup vs baseline: 1.6587x; 1.0381x over previous
//
#include <hip/hip_runtime.h>
#include <math.h>

#define N_NODES 16384
#define CIN 128
#define HOUT 256          // HEADS * OUT_CH
#define OUTC 128
#define NEG_ATT 0.2f
#define NEG_ACT 0.01f
#define BN_EPS 1e-5f

typedef short short8 __attribute__((ext_vector_type(8)));
typedef float f32x4 __attribute__((ext_vector_type(4)));

static __device__ __forceinline__ unsigned short f2bf(float f) {
    unsigned int u = __float_as_uint(f);
    unsigned int r = (u + 0x7FFFu + ((u >> 16) & 1u)) >> 16;   // round-nearest-even
    return (unsigned short)r;
}
static __device__ __forceinline__ float bf2f(unsigned short s) {
    return __uint_as_float(((unsigned int)s) << 16);
}
// unpack 8 consecutive bf16 (16B) to fp32
static __device__ __forceinline__ void loadbf8(const unsigned short* p, float* f) {
    uint4 u = *(const uint4*)p;
    f[0] = __uint_as_float(u.x << 16);
    f[1] = __uint_as_float(u.x & 0xffff0000u);
    f[2] = __uint_as_float(u.y << 16);
    f[3] = __uint_as_float(u.y & 0xffff0000u);
    f[4] = __uint_as_float(u.z << 16);
    f[5] = __uint_as_float(u.z & 0xffff0000u);
    f[6] = __uint_as_float(u.w << 16);
    f[7] = __uint_as_float(u.w & 0xffff0000u);
}

// ---------------- MFMA GEMM: h[n][o] = sum_k x[b][k][s] * lin_w[k][o] + lin_b[o] ----------
#define LDP 136
__global__ __launch_bounds__(256) void gemm_kernel(const float* __restrict__ x,
                                                   const float* __restrict__ lin_w,
                                                   const float* __restrict__ lin_b,
                                                   unsigned short* __restrict__ h,
                                                   int* __restrict__ deg,
                                                   float* __restrict__ gz) {
    __shared__ __align__(16) unsigned short A_s[64 * LDP];
    __shared__ __align__(16) unsigned short Bt_s[64 * LDP];
    const int t = threadIdx.x;
    const int bid = blockIdx.x;

    if (t < 16) deg[bid * 16 + t] = 0;            // zero deg for count_kernel
    if (bid == 0) gz[t] = 0.f;                    // zero gsum+gsumsq (256 floats)

    const int node0 = (bid >> 2) * 64;
    const int o0 = (bid & 3) * 64;
    const int b = node0 >> 13;
    const int s0 = node0 & 8191;

    const int nt = t & 15;           // n-quad
    const int kt = t >> 4;           // k-quad (0..15)
#pragma unroll
    for (int p = 0; p < 2; p++) {
        const int kb = p * 64 + kt * 4;
        float4 ar[4], br[4];
#pragma unroll
        for (int r = 0; r < 4; r++) {
            ar[r] = *(const float4*)&x[((b * CIN + kb + r) << 13) + s0 + nt * 4];
            br[r] = *(const float4*)&lin_w[(kb + r) * HOUT + o0 + nt * 4];
        }
#pragma unroll
        for (int j = 0; j < 4; j++) {
            ushort4 va, vb;
            va.x = f2bf(((const float*)&ar[0])[j]);
            va.y = f2bf(((const float*)&ar[1])[j]);
            va.z = f2bf(((const float*)&ar[2])[j]);
            va.w = f2bf(((const float*)&ar[3])[j]);
            vb.x = f2bf(((const float*)&br[0])[j]);
            vb.y = f2bf(((const float*)&br[1])[j]);
            vb.z = f2bf(((const float*)&br[2])[j]);
            vb.w = f2bf(((const float*)&br[3])[j]);
            *(ushort4*)&A_s[(nt * 4 + j) * LDP + kb] = va;
            *(ushort4*)&Bt_s[(nt * 4 + j) * LDP + kb] = vb;
        }
    }
    __syncthreads();

    const int w = t >> 6;
    const int lane = t & 63;
    const int lrow = lane & 15;
    const int lquad = lane >> 4;
    const int m0 = w * 16;

    short8 afr[4];
#pragma unroll
    for (int ks = 0; ks < 4; ks++)
        afr[ks] = *(const short8*)&A_s[(m0 + lrow) * LDP + ks * 32 + lquad * 8];

    f32x4 acc[4];
#pragma unroll
    for (int c = 0; c < 4; c++) { acc[c][0] = 0.f; acc[c][1] = 0.f; acc[c][2] = 0.f; acc[c][3] = 0.f; }

#pragma unroll
    for (int c = 0; c < 4; c++) {
#pragma unroll
        for (int ks = 0; ks < 4; ks++) {
            short8 bfr = *(const short8*)&Bt_s[(c * 16 + lrow) * LDP + ks * 32 + lquad * 8];
            acc[c] = __builtin_amdgcn_mfma_f32_16x16x32_bf16(afr[ks], bfr, acc[c], 0, 0, 0);
        }
    }

    // D mapping: col = lane&15, row = (lane>>4)*4 + reg   [m89-verified]
#pragma unroll
    for (int c = 0; c < 4; c++) {
        const int col = o0 + c * 16 + lrow;
        const float lb = lin_b[col];
#pragma unroll
        for (int r = 0; r < 4; r++) {
            const int n = node0 + m0 + lquad * 4 + r;
            h[n * HOUT + col] = f2bf(acc[c][r] + lb);
        }
    }
}

// ---------------- CSR build (grid.sync measured ~30us/sync on MI355X -> separate dispatches)
__global__ void count_kernel(const int* __restrict__ dst, int* __restrict__ deg, int E) {
    int e = blockIdx.x * 256 + threadIdx.x;
    if (e < E) atomicAdd(&deg[dst[e]], 1);
}

__global__ __launch_bounds__(1024) void scan_kernel(const int* __restrict__ deg,
                                                    int* __restrict__ row_ptr,
                                                    int* __restrict__ cursor) {
    __shared__ int sums[1024];
    const int t = threadIdx.x;
    int local[16];
    int s = 0;
#pragma unroll
    for (int k = 0; k < 16; k++) {
        local[k] = deg[t * 16 + k];
        s += local[k];
    }
    sums[t] = s;
    __syncthreads();
    for (int off = 1; off < 1024; off <<= 1) {
        int v = (t >= off) ? sums[t - off] : 0;
        __syncthreads();
        sums[t] += v;
        __syncthreads();
    }
    int run = sums[t] - s;   // exclusive
#pragma unroll
    for (int k = 0; k < 16; k++) {
        row_ptr[t * 16 + k] = run;
        cursor[t * 16 + k] = run;
        run += local[k];
    }
    if (t == 1023) row_ptr[N_NODES] = run;
}

__global__ void scatter_kernel(const int* __restrict__ edges, int* __restrict__ cursor,
                               int* __restrict__ csr, int E) {
    int e = blockIdx.x * 256 + threadIdx.x;
    if (e < E) {
        int s = edges[e];
        int d = edges[E + e];
        int p = atomicAdd(&cursor[d], 1);
        csr[p] = s;
    }
}

// ---------------- GAT: 8 ch/lane, 2 edges per wave-pass, no-max softmax (scores bounded) ---
// Layout: half = lane>>5 selects edge stream; sub = lane&31 covers channels 8*sub..8*sub+7
// (sub<16 = head0, sub>=16 = head1). Score reduce = xor{1,2,4,8} within 16-lane head group.
__global__ __launch_bounds__(256) void gat_kernel(const unsigned short* __restrict__ h,
                                                  const int* __restrict__ row_ptr,
                                                  const int* __restrict__ csr,
                                                  const float* __restrict__ att,
                                                  const float* __restrict__ gat_bias,
                                                  float* __restrict__ gat,
                                                  float* __restrict__ gsum,
                                                  float* __restrict__ gsumsq) {
    const int t = threadIdx.x;
    const int lane = t & 63;
    const int w = t >> 6;
    const int half = lane >> 5;
    const int sub = lane & 31;
    const int c0 = sub * 8;          // absolute channel base in [0,256)

    __shared__ float ssum[128], ssq[128];
    if (t < 128) { ssum[t] = 0.f; ssq[t] = 0.f; }
    __syncthreads();

    float av[8];
    *(float4*)&av[0] = *(const float4*)&att[c0];
    *(float4*)&av[4] = *(const float4*)&att[c0 + 4];
    float gb[8];
    *(float4*)&gb[0] = *(const float4*)&gat_bias[c0 & 127];
    *(float4*)&gb[4] = *(const float4*)&gat_bias[(c0 & 127) + 4];

    float st[8] = {}, sq[8] = {};

    for (int i = 0; i < 4; i++) {
        const int node = (blockIdx.x << 4) + (w << 2) + i;
        float hd[8];
        loadbf8(&h[node * HOUT + c0], hd);
        const int beg = row_ptr[node];
        const int cntT = row_ptr[node + 1] - beg + 1;   // edge 0 = self loop
        float denom = 0.f;
        float acc[8] = {};

        for (int base = 0; base < cntT; base += 8) {
            int ei[4];
            int jj[4];
#pragma unroll
            for (int u = 0; u < 4; u++) {
                ei[u] = base + 2 * u + half;
                jj[u] = (ei[u] == 0) ? node : ((ei[u] < cntT) ? csr[beg + ei[u] - 1] : node);
            }
            float hj[4][8];
            float p[4];
#pragma unroll
            for (int u = 0; u < 4; u++) {
                loadbf8(&h[jj[u] * HOUT + c0], hj[u]);
                float d = 0.f;
#pragma unroll
                for (int c = 0; c < 8; c++) {
                    float v = hj[u][c] + hd[c];
                    v = fmaxf(v, NEG_ATT * v);        // leaky_relu(v,0.2) == max(v, 0.2v)
                    d = fmaf(v, av[c], d);
                }
                p[u] = d;
            }
#pragma unroll
            for (int s = 1; s <= 8; s <<= 1) {
#pragma unroll
                for (int u = 0; u < 4; u++) p[u] += __shfl_xor(p[u], s);
            }
#pragma unroll
            for (int u = 0; u < 4; u++) {
                float wt = (ei[u] < cntT) ? __expf(p[u]) : 0.f;
                denom += wt;
#pragma unroll
                for (int c = 0; c < 8; c++) acc[c] = fmaf(wt, hj[u][c], acc[c]);
            }
        }
        // combine the two edge streams
        denom += __shfl_xor(denom, 32);
#pragma unroll
        for (int c = 0; c < 8; c++) acc[c] += __shfl_xor(acc[c], 32);
        float inv = 1.0f / denom;
        float r[8];
#pragma unroll
        for (int c = 0; c < 8; c++) r[c] = acc[c] * inv;
        // head mean: sub and sub^16 hold the same within-head channels of the two heads
#pragma unroll
        for (int c = 0; c < 8; c++) r[c] += __shfl_xor(r[c], 16);
        if (lane < 16) {
            float o[8];
#pragma unroll
            for (int c = 0; c < 8; c++) {
                o[c] = 0.5f * r[c] + gb[c];
                st[c] += o[c];
                sq[c] += o[c] * o[c];
            }
            *(float4*)&gat[node * OUTC + c0] = *(float4*)&o[0];
            *(float4*)&gat[node * OUTC + c0 + 4] = *(float4*)&o[4];
        }
    }
    if (lane < 16) {
#pragma unroll
        for (int c = 0; c < 8; c++) {
            atomicAdd(&ssum[c0 + c], st[c]);
            atomicAdd(&ssq[c0 + c], sq[c]);
        }
    }
    __syncthreads();
    if (t < 128) {
        atomicAdd(&gsum[t], ssum[t]);
        atomicAdd(&gsumsq[t], ssq[t]);
    }
}

// ---------------- epilogue: BN finalize + affine + lrelu + transpose to (B,C,D,H,W) --------
__global__ __launch_bounds__(256) void epilogue_kernel(const float* __restrict__ gat,
                                                       const float* __restrict__ gsum,
                                                       const float* __restrict__ gsumsq,
                                                       const float* __restrict__ gamma,
                                                       const float* __restrict__ beta,
                                                       float* __restrict__ out) {
    __shared__ float tile[64 * 129];
    __shared__ float sc[128], sh[128];
    const int t = threadIdx.x;
    if (t < 128) {
        const float invN = 1.0f / (float)N_NODES;
        float mean = gsum[t] * invN;
        float var = gsumsq[t] * invN - mean * mean;
        float rstd = rsqrtf(var + BN_EPS);
        float s = gamma[t] * rstd;
        sc[t] = s;
        sh[t] = beta[t] - mean * s;
    }
    __syncthreads();
    const int n0 = blockIdx.x * 64;
    const int b = n0 >> 13;
    const int s0 = n0 & 8191;
#pragma unroll
    for (int k = 0; k < 32; k++) {
        int f = t + k * 256;
        int nl = f >> 7;
        int c = f & 127;
        float v = gat[(n0 << 7) + f];
        v = v * sc[c] + sh[c];
        v = v > 0.f ? v : NEG_ACT * v;
        tile[nl * 129 + c] = v;
    }
    __syncthreads();
    const int sl = t & 63;
    const int c0 = t >> 6;
#pragma unroll
    for (int k = 0; k < 32; k++) {
        int c = c0 + (k << 2);
        out[((b * OUTC + c) << 13) + s0 + sl] = tile[sl * 129 + c];
    }
}

extern "C" void kernel_launch(void* const* d_in, const int* in_sizes, int n_in,
                              void* d_out, int out_size, void* d_ws, size_t ws_size,
                              hipStream_t stream) {
    const float* x        = (const float*)d_in[0];
    const int*   edges    = (const int*)d_in[1];
    const float* lin_w    = (const float*)d_in[2];
    const float* lin_b    = (const float*)d_in[3];
    const float* att      = (const float*)d_in[4];
    const float* gat_bias = (const float*)d_in[5];
    const float* bn_gamma = (const float*)d_in[6];
    const float* bn_beta  = (const float*)d_in[7];
    float* out = (float*)d_out;
    int E = in_sizes[1] / 2;

    char* ws = (char*)d_ws;
    unsigned short* h = (unsigned short*)(ws);            // 8 MB
    float* gat     = (float*)(ws + 8388608);              // 8 MB
    int*   deg     = (int*)(ws + 16777216);               // 64 KB
    int*   row_ptr = (int*)(ws + 16842752);               // 16385 ints
    int*   cursor  = (int*)(ws + 16908544);               // 64 KB
    int*   csr     = (int*)(ws + 16974080);               // E ints
    float* gsum    = (float*)(ws + 17825792);             // 128
    float* gsumsq  = gsum + 128;                          // 128

    gemm_kernel<<<1024, 256, 0, stream>>>(x, lin_w, lin_b, h, deg, gsum);
    count_kernel<<<(E + 255) / 256, 256, 0, stream>>>(edges + E, deg, E);
    scan_kernel<<<1, 1024, 0, stream>>>(deg, row_ptr, cursor);
    scatter_kernel<<<(E + 255) / 256, 256, 0, stream>>>(edges, cursor, csr, E);
    gat_kernel<<<N_NODES / 16, 256, 0, stream>>>(h, row_ptr, csr, att, gat_bias, gat, gsum, gsumsq);
    epilogue_kernel<<<N_NODES / 64, 256, 0, stream>>>(gat, gsum, gsumsq, bn_gamma, bn_beta, out);
}